// Round 10
// baseline (214.364 us; speedup 1.0000x reference)
//
#include <hip/hip_runtime.h>
#include <math.h>

typedef _Float16 half8  __attribute__((ext_vector_type(8)));
typedef _Float16 half4  __attribute__((ext_vector_type(4)));
typedef __fp16   fp16x2 __attribute__((ext_vector_type(2)));
typedef float    float4v __attribute__((ext_vector_type(4)));
typedef unsigned uint4v  __attribute__((ext_vector_type(4)));
typedef unsigned uint2v  __attribute__((ext_vector_type(2)));

#define NDIM   16
#define HID    128
#define NSTEP  10
#define RPW    2            // parents per WG; grid = 512 -> 2 WGs/CU
#define NROWS  48           // tile0: [x0,x1,xs0,xs1] (rows 0-3 live); tiles 1,2: tangents
#define XSTR   136          // hidden-activation row stride (halves)
#define XISTR  40           // layer-0 input row stride (halves)
#define SBS    17           // final-state row stride (fp32)

__device__ __forceinline__ float tanh_fast(float v) {
  // 1 - 2/(e^{2v}+1); rcp via v_rcp_f32 (1 trans inst, ~1e-6 rel err).
  float e = __expf(2.f * v);
  return 1.f - 2.f * __builtin_amdgcn_rcpf(e + 1.f);
}

// broadcast lane (4g+P) -> lanes 4g..4g+3 via DPP quad_perm (VALU pipe, no LDS)
template<int CTRL>
__device__ __forceinline__ float qbcast(float v) {
  int i = __builtin_amdgcn_update_dpp(0, __builtin_bit_cast(int, v), CTRL, 0xF, 0xF, true);
  return __builtin_bit_cast(float, i);
}

// packed f32->f16 conversion: v_cvt_pkrtz_f16_f32, 2 values per VALU inst
__device__ __forceinline__ unsigned pk2(float a, float b) {
  fp16x2 h = __builtin_amdgcn_cvt_pkrtz(a, b);
  return __builtin_bit_cast(unsigned, h);
}
__device__ __forceinline__ half8 h8pack(float a, float b, float c, float d,
                                        float e, float f, float g, float h) {
  uint4v u; u[0] = pk2(a,b); u[1] = pk2(c,d); u[2] = pk2(e,f); u[3] = pk2(g,h);
  return __builtin_bit_cast(half8, u);
}
__device__ __forceinline__ half4 h4pack(float a, float b, float c, float d) {
  uint2v u; u[0] = pk2(a,b); u[1] = pk2(c,d);
  return __builtin_bit_cast(half4, u);
}

// Permuted neuron storage: epilogue outputs (2 M-tiles x 4 C-rows) contiguous
// -> one ds_write_b128. Storage col c holds original neuron oneuron(c).
__device__ __forceinline__ int oneuron(int c) {
  return 32*(c >> 5) + 16*((c >> 2) & 1) + 4*((c >> 3) & 3) + (c & 3);
}

// STRUCTURE (r21): r9 skeleton + TILE0 DEDUP. Pipe arithmetic with measured
// op costs (m134: ds_*_b128 ~12cyc): 8 waves x 15 b128/phase = 1440 bank-cyc
// of a ~2170-cyc phase + 273 conflict-cyc -> LDS data pipe ~70-79% busy =
// the real bottleneck (explains why occupancy/ILP/fusion probes all lost:
// none cut LDS traffic). Tile0 stores 4 distinct cols x4-duplicated; the
// duplication is moved from STORAGE to the READ: tile0 reads remap row ->
// (ln&3) (4 lanes/address -> LDS broadcast, ~1/4 bank traffic, conflict-
// free) and tile0 writes are predicated to ln<4 (masked lanes consume no
// bank bw). Content read is bit-identical (col ln held a copy of pattern
// ln&3), so MFMA outputs and numerics are unchanged. Same trick on XI's
// state tile and the L4 wave-0 read. ~-20% LDS bank-cycles/phase.
__global__ __launch_bounds__(256, 2)
void flow_ode_kernel(const float* __restrict__ gx,  const float* __restrict__ gxs,
                     const float* __restrict__ W0,  const float* __restrict__ b0,
                     const float* __restrict__ W1,  const float* __restrict__ b1,
                     const float* __restrict__ W2,  const float* __restrict__ b2,
                     const float* __restrict__ W3,  const float* __restrict__ b3,
                     const float* __restrict__ W4,  const float* __restrict__ b4,
                     float* __restrict__ out)
{
  __shared__ __align__(16) _Float16 XT[2][NROWS][XSTR];  // hidden activations ping-pong
  __shared__ __align__(16) _Float16 XI[NROWS][XISTR];    // layer-0 input
  __shared__ float SbL[NROWS][SBS];                      // final state (solve only)

  const int tid  = threadIdx.x;
  const int mi   = tid >> 6;
  const int lane = tid & 63;
  const int q    = lane >> 4;
  const int ln   = lane & 15;
  const int g0   = blockIdx.x * RPW;

  // ---------------- weight fragments (permuted storage order) ----------------
  half8 A0[2];
  half8 A1[2][4], A2[2][4], A3[2][4];
  half8 A4[4];
  float bw[4][2][4];
  float b4r[4];

  #pragma unroll
  for (int mt = 0; mt < 2; ++mt) {
    const int m = 16*(2*mi + mt) + ln;       // original out-neuron for A-row ln
    #pragma unroll
    for (int j = 0; j < 8; ++j) {
      const int k = 8*q + j;                 // XI cols are unpermuted
      A0[mt][j] = (k < NDIM+1) ? (_Float16)W0[k*HID + m] : (_Float16)0.f;
    }
    #pragma unroll
    for (int ks = 0; ks < 4; ++ks) {
      #pragma unroll
      for (int j = 0; j < 8; ++j) {
        const int k = oneuron(32*ks + 8*q + j);   // storage col -> original neuron
        A1[mt][ks][j] = (_Float16)W1[k*HID + m];
        A2[mt][ks][j] = (_Float16)W2[k*HID + m];
        A3[mt][ks][j] = (_Float16)W3[k*HID + m];
      }
    }
  }
  #pragma unroll
  for (int ks = 0; ks < 4; ++ks)
    #pragma unroll
    for (int j = 0; j < 8; ++j)
      A4[ks][j] = (_Float16)W4[oneuron(32*ks + 8*q + j)*NDIM + ln];

  #pragma unroll
  for (int mt = 0; mt < 2; ++mt)
    #pragma unroll
    for (int r = 0; r < 4; ++r) {
      const int m = 16*(2*mi + mt) + 4*q + r;
      bw[0][mt][r] = b0[m];
      bw[1][mt][r] = b1[m];
      bw[2][mt][r] = b2[m];
      bw[3][mt][r] = b3[m];
    }
  #pragma unroll
  for (int r = 0; r < 4; ++r) b4r[r] = b4[4*q + r];

  // ---------------- RK state in registers ----------------
  // wave mi (<3) owns tile mi; lane (q,ln): row ln, dims 4q+r.
  float sbr[4], sar[4];
  if (mi == 0) {
    const int p = ln & 3;                                // [x0,x1,xs0,xs1] pattern
    const float* src = (p < 2) ? (gx + (g0 + p)*NDIM) : (gxs + (g0 + p - 2)*NDIM);
    #pragma unroll
    for (int r = 0; r < 4; ++r) sbr[r] = src[4*q + r];
  } else {
    #pragma unroll
    for (int r = 0; r < 4; ++r) sbr[r] = (ln == 4*q + r) ? 1.f : 0.f;  // tangent e_ln
  }
  #pragma unroll
  for (int r = 0; r < 4; ++r) sar[r] = 0.f;

  // ---------------- init XI (cols 0..31; 16..31 zeroed once, t(=0) included) ----------------
  for (int idx = tid; idx < NROWS*32; idx += 256)
    XI[idx >> 5][idx & 31] = (_Float16)0.f;
  __syncthreads();
  if (mi < 3) {
    half4 x4;
    #pragma unroll
    for (int r = 0; r < 4; ++r) x4[r] = (_Float16)sbr[r];
    *(half4*)&XI[mi*16 + ln][4*q] = x4;
  }
  __syncthreads();

  // phase-offset odd WGs by ~half a layer period so the two co-resident
  // barrier domains interleave LDS-port bursts instead of phase-locking.
  if (blockIdx.x & 1) __builtin_amdgcn_s_sleep(22);

  const float dt = 1.f / NSTEP;

  // epilogue: tile0 -> tanh (bias pre-folded in C-init), rows 0-3 only;
  // tiles 1,2 -> scale by quad_perm-broadcast (1-h^2) of the parent.
  auto finish = [&](float4v (&D)[2][3], int wb) {
    float hs[2][4], ss[2][4];
    #pragma unroll
    for (int mt = 0; mt < 2; ++mt)
      #pragma unroll
      for (int r = 0; r < 4; ++r) {
        const float h = tanh_fast(D[mt][0][r]);
        hs[mt][r] = h;
        ss[mt][r] = 1.f - h*h;
      }
    if (ln < 4)                                          // rows 4-15 never read
      *(half8*)&XT[wb][ln][32*mi + 8*q] =
          h8pack(hs[0][0], hs[0][1], hs[0][2], hs[0][3],
                 hs[1][0], hs[1][1], hs[1][2], hs[1][3]);
    float t1v[2][4], t2v[2][4];
    #pragma unroll
    for (int mt = 0; mt < 2; ++mt)
      #pragma unroll
      for (int r = 0; r < 4; ++r) {
        t1v[mt][r] = D[mt][1][r] * qbcast<0x00>(ss[mt][r]);   // parent 0
        t2v[mt][r] = D[mt][2][r] * qbcast<0x55>(ss[mt][r]);   // parent 1
      }
    *(half8*)&XT[wb][16 + ln][32*mi + 8*q] =
        h8pack(t1v[0][0], t1v[0][1], t1v[0][2], t1v[0][3],
               t1v[1][0], t1v[1][1], t1v[1][2], t1v[1][3]);
    *(half8*)&XT[wb][32 + ln][32*mi + 8*q] =
        h8pack(t2v[0][0], t2v[0][1], t2v[0][2], t2v[0][3],
               t2v[1][0], t2v[1][1], t2v[1][2], t2v[1][3]);
    __syncthreads();
  };

  auto mid_layer = [&](const half8 (&A)[2][4], const float (&bb)[2][4], int rb, int wb) {
    float4v D[2][3];
    #pragma unroll
    for (int mt = 0; mt < 2; ++mt)
      #pragma unroll
      for (int nt = 0; nt < 3; ++nt)
        #pragma unroll
        for (int e = 0; e < 4; ++e) D[mt][nt][e] = (nt == 0) ? bb[mt][e] : 0.f;
    __builtin_amdgcn_s_setprio(1);
    #pragma unroll
    for (int ks = 0; ks < 4; ++ks) {
      half8 Bf[3];
      // tile0: col ln's data = pattern (ln&3) -> broadcast read of row ln&3
      Bf[0] = *(const half8*)&XT[rb][ln & 3][32*ks + 8*q];
      #pragma unroll
      for (int nt = 1; nt < 3; ++nt)
        Bf[nt] = *(const half8*)&XT[rb][nt*16 + ln][32*ks + 8*q];
      #pragma unroll
      for (int nt = 0; nt < 3; ++nt) {
        D[0][nt] = __builtin_amdgcn_mfma_f32_16x16x32_f16(A[0][ks], Bf[nt], D[0][nt], 0, 0, 0);
        D[1][nt] = __builtin_amdgcn_mfma_f32_16x16x32_f16(A[1][ks], Bf[nt], D[1][nt], 0, 0, 0);
      }
    }
    __builtin_amdgcn_s_setprio(0);
    finish(D, wb);
  };

  // ---------------- 10 RK4 steps x 4 stages (stage loop fully unrolled) ----------------
  #pragma unroll 1
  for (int step = 0; step < NSTEP; ++step) {
    const float t0 = step * dt;
    #pragma unroll
    for (int stage = 0; stage < 4; ++stage) {
      { // ---- layer 0 (K = 32 from XI) -> XT[0] ----
        float4v D[2][3];
        #pragma unroll
        for (int mt = 0; mt < 2; ++mt)
          #pragma unroll
          for (int nt = 0; nt < 3; ++nt)
            #pragma unroll
            for (int e = 0; e < 4; ++e) D[mt][nt][e] = (nt == 0) ? bw[0][mt][e] : 0.f;
        half8 Bf[3];
        Bf[0] = *(const half8*)&XI[ln & 3][8*q];         // broadcast read
        #pragma unroll
        for (int nt = 1; nt < 3; ++nt)
          Bf[nt] = *(const half8*)&XI[nt*16 + ln][8*q];
        __builtin_amdgcn_s_setprio(1);
        #pragma unroll
        for (int nt = 0; nt < 3; ++nt) {
          D[0][nt] = __builtin_amdgcn_mfma_f32_16x16x32_f16(A0[0], Bf[nt], D[0][nt], 0, 0, 0);
          D[1][nt] = __builtin_amdgcn_mfma_f32_16x16x32_f16(A0[1], Bf[nt], D[1][nt], 0, 0, 0);
        }
        __builtin_amdgcn_s_setprio(0);
        finish(D, 0);
      }
      mid_layer(A1, bw[1], 0, 1);
      mid_layer(A2, bw[2], 1, 0);
      mid_layer(A3, bw[3], 0, 1);
      { // ---- layer 4 (reads XT[1]) + RK update: waves 0..2 own tiles 0..2 ----
        if (mi < 3) {
          float4v Da;
          #pragma unroll
          for (int e = 0; e < 4; ++e) Da[e] = (mi == 0) ? b4r[e] : 0.f;
          const int r4 = (mi == 0) ? (ln & 3) : (mi*16 + ln);  // tile0 dedup'd
          __builtin_amdgcn_s_setprio(1);
          #pragma unroll
          for (int ks = 0; ks < 4; ++ks) {
            half8 Ba = *(const half8*)&XT[1][r4][32*ks + 8*q];
            Da = __builtin_amdgcn_mfma_f32_16x16x32_f16(A4[ks], Ba, Da, 0, 0, 0);
          }
          __builtin_amdgcn_s_setprio(0);
          const float c_s = (stage < 2) ? 0.5f*dt : dt;
          half4 xn;
          if (stage < 3) {
            const float w_s = (stage == 0) ? 1.f : 2.f;
            float xv[4];
            #pragma unroll
            for (int r = 0; r < 4; ++r) {
              sar[r] += w_s * Da[r];
              xv[r] = sbr[r] + c_s * Da[r];
            }
            xn = h4pack(xv[0], xv[1], xv[2], xv[3]);
          } else {
            float xv[4];
            #pragma unroll
            for (int r = 0; r < 4; ++r) {
              const float nb = sbr[r] + (dt * (1.f/6.f)) * (sar[r] + Da[r]);
              sbr[r] = nb;
              sar[r] = 0.f;
              xv[r] = nb;
            }
            xn = h4pack(xv[0], xv[1], xv[2], xv[3]);
          }
          if (mi != 0 || ln < 4)                         // XI tile0 rows 4-15 dead
            *(half4*)&XI[mi*16 + ln][4*q] = xn;
          if (mi == 0 && q == 0 && ln < 4)
            XI[ln][16] = (_Float16)(t0 + ((stage < 2) ? 0.5f*dt : dt));  // t column
        }
        __syncthreads();
      }
    }
  }

  // ---------------- dump state, then per-parent solve ----------------
  if (mi < 3) {
    #pragma unroll
    for (int r = 0; r < 4; ++r)
      SbL[mi*16 + ln][4*q + r] = sbr[r];
  }
  __syncthreads();

  if (mi < RPW) {
    const int p    = mi;
    const int jj   = ln;
    const int base = lane & 48;
    float c[NDIM], gv[NDIM], G[NDIM];
    #pragma unroll
    for (int i = 0; i < NDIM; ++i) c[i] = SbL[16 + 16*p + jj][i];   // J[:, jj]
    float n2 = 0.f;
    #pragma unroll
    for (int i = 0; i < NDIM; ++i) {
      // tile0 col layout [x0,x1,xs0,xs1]: x_p at col p, xs_p at col 2+p
      gv[i] = SbL[p][i] - SbL[2 + p][i];                            // y - y*
      n2 += gv[i]*gv[i];
    }
    const float rinv = 1.f / (sqrtf(n2) + 1e-8f);
    float rhs = 0.f;
    #pragma unroll
    for (int i = 0; i < NDIM; ++i) rhs += c[i] * gv[i];
    rhs *= rinv;
    #pragma unroll
    for (int k = 0; k < NDIM; ++k) {
      float acc = (k == jj) ? 1e-6f : 0.f;
      #pragma unroll
      for (int i = 0; i < NDIM; ++i)
        acc += c[i] * __shfl(c[i], base + k, 64);
      G[k] = acc;
    }
    #pragma unroll
    for (int k = 0; k < NDIM-1; ++k) {
      const float piv  = __shfl(G[k], base + k, 64);
      const float prhs = __shfl(rhs,  base + k, 64);
      const float f = (jj > k) ? G[k] / piv : 0.f;
      #pragma unroll
      for (int cc = k; cc < NDIM; ++cc)
        G[cc] -= f * __shfl(G[cc], base + k, 64);
      rhs -= f * prhs;
    }
    float sol = 0.f;
    #pragma unroll
    for (int k = NDIM-1; k >= 0; --k) {
      const float piv = __shfl(G[k], base + k, 64);
      const float pr  = __shfl(rhs,  base + k, 64);
      const float xk  = pr / piv;
      if (jj == k) sol = xk;
      if (jj <  k) rhs -= G[k] * xk;
    }
    if (lane < NDIM)
      out[(g0 + p)*NDIM + jj] = -sol;
  }
}

extern "C" void kernel_launch(void* const* d_in, const int* in_sizes, int n_in,
                              void* d_out, int out_size, void* d_ws, size_t ws_size,
                              hipStream_t stream) {
  (void)in_sizes; (void)n_in; (void)d_ws; (void)ws_size; (void)out_size;
  flow_ode_kernel<<<dim3(512), dim3(256), 0, stream>>>(
      (const float*)d_in[0],  (const float*)d_in[1],
      (const float*)d_in[2],  (const float*)d_in[3],
      (const float*)d_in[4],  (const float*)d_in[5],
      (const float*)d_in[6],  (const float*)d_in[7],
      (const float*)d_in[8],  (const float*)d_in[9],
      (const float*)d_in[10], (const float*)d_in[11],
      (float*)d_out);
}

// Round 11
// 212.571 us; speedup vs baseline: 1.0084x; 1.0084x over previous
//
#include <hip/hip_runtime.h>
#include <math.h>

typedef _Float16 half8  __attribute__((ext_vector_type(8)));
typedef _Float16 half4  __attribute__((ext_vector_type(4)));
typedef __fp16   fp16x2 __attribute__((ext_vector_type(2)));
typedef float    float4v __attribute__((ext_vector_type(4)));
typedef unsigned uint4v  __attribute__((ext_vector_type(4)));
typedef unsigned uint2v  __attribute__((ext_vector_type(2)));

#define NDIM   16
#define HID    128
#define NSTEP  10
#define RPW    2            // parents per WG; grid = 512 -> 2 WGs/CU
#define NROWS  48           // tile0: [x0,x1,xs0,xs1] (rows 0-3 live); tiles 1,2: tangents
#define XSTR   136          // hidden-activation row stride (halves)
#define XISTR  40           // layer-0 input row stride (halves)
#define SBS    17           // final-state row stride (fp32)

__device__ __forceinline__ float tanh_fast(float v) {
  // 1 - 2/(e^{2v}+1); rcp via v_rcp_f32 (1 trans inst, ~1e-6 rel err).
  float e = __expf(2.f * v);
  return 1.f - 2.f * __builtin_amdgcn_rcpf(e + 1.f);
}

// broadcast lane (4g+P) -> lanes 4g..4g+3 via DPP quad_perm (VALU pipe, no LDS)
template<int CTRL>
__device__ __forceinline__ float qbcast(float v) {
  int i = __builtin_amdgcn_update_dpp(0, __builtin_bit_cast(int, v), CTRL, 0xF, 0xF, true);
  return __builtin_bit_cast(float, i);
}

// packed f32->f16 conversion: v_cvt_pkrtz_f16_f32, 2 values per VALU inst
__device__ __forceinline__ unsigned pk2(float a, float b) {
  fp16x2 h = __builtin_amdgcn_cvt_pkrtz(a, b);
  return __builtin_bit_cast(unsigned, h);
}
__device__ __forceinline__ half8 h8pack(float a, float b, float c, float d,
                                        float e, float f, float g, float h) {
  uint4v u; u[0] = pk2(a,b); u[1] = pk2(c,d); u[2] = pk2(e,f); u[3] = pk2(g,h);
  return __builtin_bit_cast(half8, u);
}
__device__ __forceinline__ half4 h4pack(float a, float b, float c, float d) {
  uint2v u; u[0] = pk2(a,b); u[1] = pk2(c,d);
  return __builtin_bit_cast(half4, u);
}

// Permuted neuron storage: epilogue outputs (2 M-tiles x 4 C-rows) contiguous
// -> one ds_write_b128. Storage col c holds original neuron oneuron(c).
__device__ __forceinline__ int oneuron(int c) {
  return 32*(c >> 5) + 16*((c >> 2) & 1) + 4*((c >> 3) & 3) + (c & 3);
}

// STRUCTURE (r22): r10 kernel (r9 skeleton + tile0 dedup, steady 168-171us)
// with the inter-WG phase offset rescaled to the new phase length.
// Confirmed model: LDS data pipe is the dominant consumer (~50% post-dedup);
// the two co-resident WGs are phase-offset so their LDS bursts interleave.
// s_sleep(22) (~1408cyc) was tuned for the r0 ~2340-cyc phase; phases are
// now ~2000 cyc -> half-period offset ~1000-1100 cyc -> s_sleep(17).
// History: r12 more-waves spilled; r13 dual-pipeline ILP lost; r14/r19
// phase-fusions spilled/regressed; r16 swizzle wrong-math; pk2 -8%;
// tile0 dedup -8%; setprio neutral-kept.
__global__ __launch_bounds__(256, 2)
void flow_ode_kernel(const float* __restrict__ gx,  const float* __restrict__ gxs,
                     const float* __restrict__ W0,  const float* __restrict__ b0,
                     const float* __restrict__ W1,  const float* __restrict__ b1,
                     const float* __restrict__ W2,  const float* __restrict__ b2,
                     const float* __restrict__ W3,  const float* __restrict__ b3,
                     const float* __restrict__ W4,  const float* __restrict__ b4,
                     float* __restrict__ out)
{
  __shared__ __align__(16) _Float16 XT[2][NROWS][XSTR];  // hidden activations ping-pong
  __shared__ __align__(16) _Float16 XI[NROWS][XISTR];    // layer-0 input
  __shared__ float SbL[NROWS][SBS];                      // final state (solve only)

  const int tid  = threadIdx.x;
  const int mi   = tid >> 6;
  const int lane = tid & 63;
  const int q    = lane >> 4;
  const int ln   = lane & 15;
  const int g0   = blockIdx.x * RPW;

  // ---------------- weight fragments (permuted storage order) ----------------
  half8 A0[2];
  half8 A1[2][4], A2[2][4], A3[2][4];
  half8 A4[4];
  float bw[4][2][4];
  float b4r[4];

  #pragma unroll
  for (int mt = 0; mt < 2; ++mt) {
    const int m = 16*(2*mi + mt) + ln;       // original out-neuron for A-row ln
    #pragma unroll
    for (int j = 0; j < 8; ++j) {
      const int k = 8*q + j;                 // XI cols are unpermuted
      A0[mt][j] = (k < NDIM+1) ? (_Float16)W0[k*HID + m] : (_Float16)0.f;
    }
    #pragma unroll
    for (int ks = 0; ks < 4; ++ks) {
      #pragma unroll
      for (int j = 0; j < 8; ++j) {
        const int k = oneuron(32*ks + 8*q + j);   // storage col -> original neuron
        A1[mt][ks][j] = (_Float16)W1[k*HID + m];
        A2[mt][ks][j] = (_Float16)W2[k*HID + m];
        A3[mt][ks][j] = (_Float16)W3[k*HID + m];
      }
    }
  }
  #pragma unroll
  for (int ks = 0; ks < 4; ++ks)
    #pragma unroll
    for (int j = 0; j < 8; ++j)
      A4[ks][j] = (_Float16)W4[oneuron(32*ks + 8*q + j)*NDIM + ln];

  #pragma unroll
  for (int mt = 0; mt < 2; ++mt)
    #pragma unroll
    for (int r = 0; r < 4; ++r) {
      const int m = 16*(2*mi + mt) + 4*q + r;
      bw[0][mt][r] = b0[m];
      bw[1][mt][r] = b1[m];
      bw[2][mt][r] = b2[m];
      bw[3][mt][r] = b3[m];
    }
  #pragma unroll
  for (int r = 0; r < 4; ++r) b4r[r] = b4[4*q + r];

  // ---------------- RK state in registers ----------------
  // wave mi (<3) owns tile mi; lane (q,ln): row ln, dims 4q+r.
  float sbr[4], sar[4];
  if (mi == 0) {
    const int p = ln & 3;                                // [x0,x1,xs0,xs1] pattern
    const float* src = (p < 2) ? (gx + (g0 + p)*NDIM) : (gxs + (g0 + p - 2)*NDIM);
    #pragma unroll
    for (int r = 0; r < 4; ++r) sbr[r] = src[4*q + r];
  } else {
    #pragma unroll
    for (int r = 0; r < 4; ++r) sbr[r] = (ln == 4*q + r) ? 1.f : 0.f;  // tangent e_ln
  }
  #pragma unroll
  for (int r = 0; r < 4; ++r) sar[r] = 0.f;

  // ---------------- init XI (cols 0..31; 16..31 zeroed once, t(=0) included) ----------------
  for (int idx = tid; idx < NROWS*32; idx += 256)
    XI[idx >> 5][idx & 31] = (_Float16)0.f;
  __syncthreads();
  if (mi < 3) {
    half4 x4;
    #pragma unroll
    for (int r = 0; r < 4; ++r) x4[r] = (_Float16)sbr[r];
    *(half4*)&XI[mi*16 + ln][4*q] = x4;
  }
  __syncthreads();

  // phase-offset odd WGs by ~half the (post-dedup) phase period so the two
  // co-resident barrier domains interleave LDS-port bursts.
  if (blockIdx.x & 1) __builtin_amdgcn_s_sleep(17);

  const float dt = 1.f / NSTEP;

  // epilogue: tile0 -> tanh (bias pre-folded in C-init), rows 0-3 only;
  // tiles 1,2 -> scale by quad_perm-broadcast (1-h^2) of the parent.
  auto finish = [&](float4v (&D)[2][3], int wb) {
    float hs[2][4], ss[2][4];
    #pragma unroll
    for (int mt = 0; mt < 2; ++mt)
      #pragma unroll
      for (int r = 0; r < 4; ++r) {
        const float h = tanh_fast(D[mt][0][r]);
        hs[mt][r] = h;
        ss[mt][r] = 1.f - h*h;
      }
    if (ln < 4)                                          // rows 4-15 never read
      *(half8*)&XT[wb][ln][32*mi + 8*q] =
          h8pack(hs[0][0], hs[0][1], hs[0][2], hs[0][3],
                 hs[1][0], hs[1][1], hs[1][2], hs[1][3]);
    float t1v[2][4], t2v[2][4];
    #pragma unroll
    for (int mt = 0; mt < 2; ++mt)
      #pragma unroll
      for (int r = 0; r < 4; ++r) {
        t1v[mt][r] = D[mt][1][r] * qbcast<0x00>(ss[mt][r]);   // parent 0
        t2v[mt][r] = D[mt][2][r] * qbcast<0x55>(ss[mt][r]);   // parent 1
      }
    *(half8*)&XT[wb][16 + ln][32*mi + 8*q] =
        h8pack(t1v[0][0], t1v[0][1], t1v[0][2], t1v[0][3],
               t1v[1][0], t1v[1][1], t1v[1][2], t1v[1][3]);
    *(half8*)&XT[wb][32 + ln][32*mi + 8*q] =
        h8pack(t2v[0][0], t2v[0][1], t2v[0][2], t2v[0][3],
               t2v[1][0], t2v[1][1], t2v[1][2], t2v[1][3]);
    __syncthreads();
  };

  auto mid_layer = [&](const half8 (&A)[2][4], const float (&bb)[2][4], int rb, int wb) {
    float4v D[2][3];
    #pragma unroll
    for (int mt = 0; mt < 2; ++mt)
      #pragma unroll
      for (int nt = 0; nt < 3; ++nt)
        #pragma unroll
        for (int e = 0; e < 4; ++e) D[mt][nt][e] = (nt == 0) ? bb[mt][e] : 0.f;
    __builtin_amdgcn_s_setprio(1);
    #pragma unroll
    for (int ks = 0; ks < 4; ++ks) {
      half8 Bf[3];
      // tile0: col ln's data = pattern (ln&3) -> broadcast read of row ln&3
      Bf[0] = *(const half8*)&XT[rb][ln & 3][32*ks + 8*q];
      #pragma unroll
      for (int nt = 1; nt < 3; ++nt)
        Bf[nt] = *(const half8*)&XT[rb][nt*16 + ln][32*ks + 8*q];
      #pragma unroll
      for (int nt = 0; nt < 3; ++nt) {
        D[0][nt] = __builtin_amdgcn_mfma_f32_16x16x32_f16(A[0][ks], Bf[nt], D[0][nt], 0, 0, 0);
        D[1][nt] = __builtin_amdgcn_mfma_f32_16x16x32_f16(A[1][ks], Bf[nt], D[1][nt], 0, 0, 0);
      }
    }
    __builtin_amdgcn_s_setprio(0);
    finish(D, wb);
  };

  // ---------------- 10 RK4 steps x 4 stages (stage loop fully unrolled) ----------------
  #pragma unroll 1
  for (int step = 0; step < NSTEP; ++step) {
    const float t0 = step * dt;
    #pragma unroll
    for (int stage = 0; stage < 4; ++stage) {
      { // ---- layer 0 (K = 32 from XI) -> XT[0] ----
        float4v D[2][3];
        #pragma unroll
        for (int mt = 0; mt < 2; ++mt)
          #pragma unroll
          for (int nt = 0; nt < 3; ++nt)
            #pragma unroll
            for (int e = 0; e < 4; ++e) D[mt][nt][e] = (nt == 0) ? bw[0][mt][e] : 0.f;
        half8 Bf[3];
        Bf[0] = *(const half8*)&XI[ln & 3][8*q];         // broadcast read
        #pragma unroll
        for (int nt = 1; nt < 3; ++nt)
          Bf[nt] = *(const half8*)&XI[nt*16 + ln][8*q];
        __builtin_amdgcn_s_setprio(1);
        #pragma unroll
        for (int nt = 0; nt < 3; ++nt) {
          D[0][nt] = __builtin_amdgcn_mfma_f32_16x16x32_f16(A0[0], Bf[nt], D[0][nt], 0, 0, 0);
          D[1][nt] = __builtin_amdgcn_mfma_f32_16x16x32_f16(A0[1], Bf[nt], D[1][nt], 0, 0, 0);
        }
        __builtin_amdgcn_s_setprio(0);
        finish(D, 0);
      }
      mid_layer(A1, bw[1], 0, 1);
      mid_layer(A2, bw[2], 1, 0);
      mid_layer(A3, bw[3], 0, 1);
      { // ---- layer 4 (reads XT[1]) + RK update: waves 0..2 own tiles 0..2 ----
        if (mi < 3) {
          float4v Da;
          #pragma unroll
          for (int e = 0; e < 4; ++e) Da[e] = (mi == 0) ? b4r[e] : 0.f;
          const int r4 = (mi == 0) ? (ln & 3) : (mi*16 + ln);  // tile0 dedup'd
          __builtin_amdgcn_s_setprio(1);
          #pragma unroll
          for (int ks = 0; ks < 4; ++ks) {
            half8 Ba = *(const half8*)&XT[1][r4][32*ks + 8*q];
            Da = __builtin_amdgcn_mfma_f32_16x16x32_f16(A4[ks], Ba, Da, 0, 0, 0);
          }
          __builtin_amdgcn_s_setprio(0);
          const float c_s = (stage < 2) ? 0.5f*dt : dt;
          half4 xn;
          if (stage < 3) {
            const float w_s = (stage == 0) ? 1.f : 2.f;
            float xv[4];
            #pragma unroll
            for (int r = 0; r < 4; ++r) {
              sar[r] += w_s * Da[r];
              xv[r] = sbr[r] + c_s * Da[r];
            }
            xn = h4pack(xv[0], xv[1], xv[2], xv[3]);
          } else {
            float xv[4];
            #pragma unroll
            for (int r = 0; r < 4; ++r) {
              const float nb = sbr[r] + (dt * (1.f/6.f)) * (sar[r] + Da[r]);
              sbr[r] = nb;
              sar[r] = 0.f;
              xv[r] = nb;
            }
            xn = h4pack(xv[0], xv[1], xv[2], xv[3]);
          }
          if (mi != 0 || ln < 4)                         // XI tile0 rows 4-15 dead
            *(half4*)&XI[mi*16 + ln][4*q] = xn;
          if (mi == 0 && q == 0 && ln < 4)
            XI[ln][16] = (_Float16)(t0 + ((stage < 2) ? 0.5f*dt : dt));  // t column
        }
        __syncthreads();
      }
    }
  }

  // ---------------- dump state, then per-parent solve ----------------
  if (mi < 3) {
    #pragma unroll
    for (int r = 0; r < 4; ++r)
      SbL[mi*16 + ln][4*q + r] = sbr[r];
  }
  __syncthreads();

  if (mi < RPW) {
    const int p    = mi;
    const int jj   = ln;
    const int base = lane & 48;
    float c[NDIM], gv[NDIM], G[NDIM];
    #pragma unroll
    for (int i = 0; i < NDIM; ++i) c[i] = SbL[16 + 16*p + jj][i];   // J[:, jj]
    float n2 = 0.f;
    #pragma unroll
    for (int i = 0; i < NDIM; ++i) {
      // tile0 col layout [x0,x1,xs0,xs1]: x_p at col p, xs_p at col 2+p
      gv[i] = SbL[p][i] - SbL[2 + p][i];                            // y - y*
      n2 += gv[i]*gv[i];
    }
    const float rinv = 1.f / (sqrtf(n2) + 1e-8f);
    float rhs = 0.f;
    #pragma unroll
    for (int i = 0; i < NDIM; ++i) rhs += c[i] * gv[i];
    rhs *= rinv;
    #pragma unroll
    for (int k = 0; k < NDIM; ++k) {
      float acc = (k == jj) ? 1e-6f : 0.f;
      #pragma unroll
      for (int i = 0; i < NDIM; ++i)
        acc += c[i] * __shfl(c[i], base + k, 64);
      G[k] = acc;
    }
    #pragma unroll
    for (int k = 0; k < NDIM-1; ++k) {
      const float piv  = __shfl(G[k], base + k, 64);
      const float prhs = __shfl(rhs,  base + k, 64);
      const float f = (jj > k) ? G[k] / piv : 0.f;
      #pragma unroll
      for (int cc = k; cc < NDIM; ++cc)
        G[cc] -= f * __shfl(G[cc], base + k, 64);
      rhs -= f * prhs;
    }
    float sol = 0.f;
    #pragma unroll
    for (int k = NDIM-1; k >= 0; --k) {
      const float piv = __shfl(G[k], base + k, 64);
      const float pr  = __shfl(rhs,  base + k, 64);
      const float xk  = pr / piv;
      if (jj == k) sol = xk;
      if (jj <  k) rhs -= G[k] * xk;
    }
    if (lane < NDIM)
      out[(g0 + p)*NDIM + jj] = -sol;
  }
}

extern "C" void kernel_launch(void* const* d_in, const int* in_sizes, int n_in,
                              void* d_out, int out_size, void* d_ws, size_t ws_size,
                              hipStream_t stream) {
  (void)in_sizes; (void)n_in; (void)d_ws; (void)ws_size; (void)out_size;
  flow_ode_kernel<<<dim3(512), dim3(256), 0, stream>>>(
      (const float*)d_in[0],  (const float*)d_in[1],
      (const float*)d_in[2],  (const float*)d_in[3],
      (const float*)d_in[4],  (const float*)d_in[5],
      (const float*)d_in[6],  (const float*)d_in[7],
      (const float*)d_in[8],  (const float*)d_in[9],
      (const float*)d_in[10], (const float*)d_in[11],
      (float*)d_out);
}